// Round 7
// baseline (122.931 us; speedup 1.0000x reference)
//
#include <hip/hip_runtime.h>
#include <math.h>

#define BATCH 2
#define SEQ 2048
#define BL (BATCH * SEQ)      // 4096
#define EMBED 1024
#define PROJ 512
#define NHEADS 8
#define HDIM 64
#define QKVN (3 * PROJ)       // 1536 fused q|k|v columns
#define KVSPLIT 2
#define KVHALF (SEQ / KVSPLIT)   // 1024

typedef _Float16 half8 __attribute__((ext_vector_type(8)));
typedef float floatx4 __attribute__((ext_vector_type(4)));

// ---------------------------------------------------------------------------
// Weight prep: dst[n][k] = (f16)(src[k][n] * scale)   (transpose + convert)
// ---------------------------------------------------------------------------
__global__ __launch_bounds__(256) void trconv(const float* __restrict__ src,
                                              _Float16* __restrict__ dst,
                                              int K, int N, float scale) {
    __shared__ float tile[64][65];
    const int t  = threadIdx.x;
    const int n0 = blockIdx.x * 64;
    const int k0 = blockIdx.y * 64;
    const int tx = t & 63;
    const int ty = t >> 6;   // 0..3
#pragma unroll
    for (int i = 0; i < 16; ++i) {
        int k = ty * 16 + i;
        tile[k][tx] = src[(size_t)(k0 + k) * N + n0 + tx];
    }
    __syncthreads();
#pragma unroll
    for (int i = 0; i < 16; ++i) {
        int n = ty * 16 + i;
        dst[(size_t)(n0 + n) * K + k0 + tx] = (_Float16)(tile[tx][n] * scale);
    }
}

// ---------------------------------------------------------------------------
// V pre-transpose: v (f16, rows stride QKVN, head h cols 64) -> vt[b][h][d][SEQ]
// ---------------------------------------------------------------------------
__global__ __launch_bounds__(256) void trans_v(const _Float16* __restrict__ v,
                                               _Float16* __restrict__ vt) {
    __shared__ _Float16 tile[64][72];
    const int t  = threadIdx.x;
    const int t0 = blockIdx.x * 64;
    const int h  = blockIdx.y;
    const int b  = blockIdx.z;
    {
        const int r = t >> 2, c0 = (t & 3) * 16;
        const _Float16* src = v + (size_t)(b * SEQ + t0 + r) * QKVN + h * HDIM + c0;
        *reinterpret_cast<half8*>(&tile[r][c0])     = *reinterpret_cast<const half8*>(src);
        *reinterpret_cast<half8*>(&tile[r][c0 + 8]) = *reinterpret_cast<const half8*>(src + 8);
    }
    __syncthreads();
    {
        const int c = t >> 2, k0 = (t & 3) * 16;
        half8 o1, o2;
#pragma unroll
        for (int i = 0; i < 8; ++i) { o1[i] = tile[k0 + i][c]; o2[i] = tile[k0 + 8 + i][c]; }
        _Float16* dst = vt + ((size_t)(b * NHEADS + h) * HDIM + c) * SEQ + t0 + k0;
        *reinterpret_cast<half8*>(dst)     = o1;
        *reinterpret_cast<half8*>(dst + 8) = o2;
    }
}

// ---------------------------------------------------------------------------
// f16 MFMA GEMM: C[M][N] = A[M][K] @ Bt[N][K]^T (+bias, relu), fp32 accum.
// Block tile 64(M) x 64(N), BK=32, 256 threads = 4 waves (2x2 of 32x32).
// ---------------------------------------------------------------------------
template <int A_F32, int BIASRELU, int C_F32>
__global__ __launch_bounds__(256) void gemm_mfma(const void* __restrict__ Ap,
                                                 const _Float16* __restrict__ Bt,
                                                 const float* __restrict__ bias,
                                                 void* __restrict__ Cp,
                                                 int M, int N, int K) {
    __shared__ _Float16 Ah[64][40];
    __shared__ _Float16 Bh[64][40];

    const int t  = threadIdx.x;
    const int w  = t >> 6;
    const int l  = t & 63;
    const int lr = l & 15;
    const int lg = l >> 4;
    const int bm = blockIdx.y * 64;
    const int bn = blockIdx.x * 64;
    const int wr = w >> 1;       // 0..1 -> m offset wr*32
    const int wc = w & 1;        // 0..1 -> n offset wc*32

    const int ar = t >> 2, ac = (t & 3) * 8;   // both A and B staging: 64 rows x 32 k

    floatx4 acc[2][2];
#pragma unroll
    for (int i = 0; i < 2; ++i)
#pragma unroll
        for (int j = 0; j < 2; ++j) acc[i][j] = (floatx4){0.f, 0.f, 0.f, 0.f};

    float4 af0, af1;
    half8 areg, breg;

    const float* Af = (const float*)Ap;
    const _Float16* Ah16 = (const _Float16*)Ap;

    if (A_F32) {
        af0 = *reinterpret_cast<const float4*>(&Af[(size_t)(bm + ar) * K + ac]);
        af1 = *reinterpret_cast<const float4*>(&Af[(size_t)(bm + ar) * K + ac + 4]);
    } else {
        areg = *reinterpret_cast<const half8*>(&Ah16[(size_t)(bm + ar) * K + ac]);
    }
    breg = *reinterpret_cast<const half8*>(&Bt[(size_t)(bn + ar) * K + ac]);

    for (int kt = 0; kt < K; kt += 32) {
        if (A_F32) {
            half8 hcv;
            hcv[0] = (_Float16)af0.x; hcv[1] = (_Float16)af0.y;
            hcv[2] = (_Float16)af0.z; hcv[3] = (_Float16)af0.w;
            hcv[4] = (_Float16)af1.x; hcv[5] = (_Float16)af1.y;
            hcv[6] = (_Float16)af1.z; hcv[7] = (_Float16)af1.w;
            *reinterpret_cast<half8*>(&Ah[ar][ac]) = hcv;
        } else {
            *reinterpret_cast<half8*>(&Ah[ar][ac]) = areg;
        }
        *reinterpret_cast<half8*>(&Bh[ar][ac]) = breg;
        __syncthreads();

        if (kt + 32 < K) {
            if (A_F32) {
                af0 = *reinterpret_cast<const float4*>(&Af[(size_t)(bm + ar) * K + kt + 32 + ac]);
                af1 = *reinterpret_cast<const float4*>(&Af[(size_t)(bm + ar) * K + kt + 32 + ac + 4]);
            } else {
                areg = *reinterpret_cast<const half8*>(&Ah16[(size_t)(bm + ar) * K + kt + 32 + ac]);
            }
            breg = *reinterpret_cast<const half8*>(&Bt[(size_t)(bn + ar) * K + kt + 32 + ac]);
        }

        half8 afr[2], bfr[2];
#pragma unroll
        for (int mf = 0; mf < 2; ++mf)
            afr[mf] = *reinterpret_cast<const half8*>(&Ah[wr * 32 + mf * 16 + lr][lg * 8]);
#pragma unroll
        for (int nf = 0; nf < 2; ++nf)
            bfr[nf] = *reinterpret_cast<const half8*>(&Bh[wc * 32 + nf * 16 + lr][lg * 8]);
#pragma unroll
        for (int mf = 0; mf < 2; ++mf)
#pragma unroll
            for (int nf = 0; nf < 2; ++nf)
                acc[mf][nf] = __builtin_amdgcn_mfma_f32_16x16x32_f16(afr[mf], bfr[nf], acc[mf][nf], 0, 0, 0);

        __syncthreads();
    }

#pragma unroll
    for (int mf = 0; mf < 2; ++mf)
#pragma unroll
        for (int nf = 0; nf < 2; ++nf) {
            const int n = bn + wc * 32 + nf * 16 + lr;
            float bs = 0.f;
            if (BIASRELU) bs = bias[n];
#pragma unroll
            for (int r = 0; r < 4; ++r) {
                const int m = bm + wr * 32 + mf * 16 + lg * 4 + r;
                float v = acc[mf][nf][r];
                if (BIASRELU) v = fmaxf(v + bs, 0.f);
                if (C_F32)
                    ((float*)Cp)[(size_t)m * N + n] = v;
                else
                    ((_Float16*)Cp)[(size_t)m * N + n] = (_Float16)v;
            }
        }
}

// ---------------------------------------------------------------------------
// f16-MFMA flash attention, KV-split 2-way, exp2-domain softmax.
// Q,K f16 rows stride QKVN (log2e*scale folded into Wq); Vt[b][h][d][SEQ].
// Grid: ((SEQ/64)*KVSPLIT, H, B), block 256 = 4 waves x 16 q rows.
// Partials: Op[kvh][b][h][q][d] f32 (un-normalized), ml[kvh][b][h][q] float2.
// ---------------------------------------------------------------------------
__global__ __launch_bounds__(256) void attn_part(const _Float16* __restrict__ Q,
                                                 const _Float16* __restrict__ K,
                                                 const _Float16* __restrict__ Vt,
                                                 float* __restrict__ Op,
                                                 float* __restrict__ ml) {
    __shared__ _Float16 Ks[64][72];
    __shared__ _Float16 Vs[64][72];
    __shared__ _Float16 Ps[4][16][72];

    const int t  = threadIdx.x;
    const int w  = t >> 6;
    const int l  = t & 63;
    const int lr = l & 15;
    const int lg = l >> 4;

    const int qt  = blockIdx.x >> 1;
    const int kvh = blockIdx.x & 1;
    const int q0  = qt * 64;
    const int h   = blockIdx.y;
    const int b   = blockIdx.z;
    const size_t base  = (size_t)b * SEQ * QKVN + (size_t)h * HDIM;
    const size_t vbase = (size_t)(b * NHEADS + h) * HDIM * SEQ;
    const size_t poff  = (((size_t)kvh * BATCH + b) * NHEADS + h) * SEQ;  // partial row base

    const int kt0  = kvh * KVHALF;
    const int kend = kt0 + KVHALF;

    // ---- Q fragments (B-operand layout), 16 q rows per wave ----
    half8 qf[2];
#pragma unroll
    for (int s = 0; s < 2; ++s) {
        const int qrow = q0 + w * 16 + lr;
        qf[s] = *reinterpret_cast<const half8*>(
            &Q[base + (size_t)qrow * QKVN + s * 32 + lg * 8]);
    }

    floatx4 o_acc[4];
#pragma unroll
    for (int j = 0; j < 4; ++j) o_acc[j] = (floatx4){0.f, 0.f, 0.f, 0.f};

    float m_s = -1e30f;
    float l_s = 0.f;

    const int rkv = t >> 2;
    const int d0  = (t & 3) * 16;

    // ---- initial prefetch ----
    half8 ka0, ka1, va0, va1;
    {
        const _Float16* kp = K + base + (size_t)(kt0 + rkv) * QKVN + d0;
        ka0 = *reinterpret_cast<const half8*>(kp);
        ka1 = *reinterpret_cast<const half8*>(kp + 8);
        const _Float16* vp = Vt + vbase + (size_t)rkv * SEQ + kt0 + d0;
        va0 = *reinterpret_cast<const half8*>(vp);
        va1 = *reinterpret_cast<const half8*>(vp + 8);
    }

    for (int kt = kt0; kt < kend; kt += 64) {
        *reinterpret_cast<half8*>(&Ks[rkv][d0])     = ka0;
        *reinterpret_cast<half8*>(&Ks[rkv][d0 + 8]) = ka1;
        *reinterpret_cast<half8*>(&Vs[rkv][d0])     = va0;
        *reinterpret_cast<half8*>(&Vs[rkv][d0 + 8]) = va1;
        __syncthreads();

        if (kt + 64 < kend) {
            const _Float16* kp = K + base + (size_t)(kt + 64 + rkv) * QKVN + d0;
            ka0 = *reinterpret_cast<const half8*>(kp);
            ka1 = *reinterpret_cast<const half8*>(kp + 8);
            const _Float16* vp = Vt + vbase + (size_t)rkv * SEQ + kt + 64 + d0;
            va0 = *reinterpret_cast<const half8*>(vp);
            va1 = *reinterpret_cast<const half8*>(vp + 8);
        }

        // ---- S^T = K @ Q^T (scores already in log2 domain) ----
        floatx4 stv[4];
#pragma unroll
        for (int i = 0; i < 4; ++i) stv[i] = (floatx4){0.f, 0.f, 0.f, 0.f};
#pragma unroll
        for (int s = 0; s < 2; ++s)
#pragma unroll
            for (int mf = 0; mf < 4; ++mf) {
                half8 kfr = *reinterpret_cast<const half8*>(&Ks[mf * 16 + lr][s * 32 + lg * 8]);
                stv[mf] = __builtin_amdgcn_mfma_f32_16x16x32_f16(kfr, qf[s], stv[mf], 0, 0, 0);
            }

        // ---- online softmax (exp2 domain) ----
        float tm = -1e30f;
#pragma unroll
        for (int mf = 0; mf < 4; ++mf)
#pragma unroll
            for (int r = 0; r < 4; ++r) tm = fmaxf(tm, stv[mf][r]);
        tm = fmaxf(tm, __shfl_xor(tm, 16));
        tm = fmaxf(tm, __shfl_xor(tm, 32));
        float mn = fmaxf(m_s, tm);
        float fscale = exp2f(m_s - mn);
        m_s = mn;
        float sum = 0.f;
#pragma unroll
        for (int mf = 0; mf < 4; ++mf)
#pragma unroll
            for (int r = 0; r < 4; ++r) {
                float p = exp2f(stv[mf][r] - mn);
                stv[mf][r] = p;
                sum += p;
            }
        sum += __shfl_xor(sum, 16);
        sum += __shfl_xor(sum, 32);
        l_s = l_s * fscale + sum;

        // ---- P -> wave-private LDS (PV A-layout) ----
#pragma unroll
        for (int mf = 0; mf < 4; ++mf)
#pragma unroll
            for (int rp = 0; rp < 2; ++rp) {
                union { _Float16 hh[2]; unsigned int u; } pk;
                pk.hh[0] = (_Float16)stv[mf][2 * rp];
                pk.hh[1] = (_Float16)stv[mf][2 * rp + 1];
                *reinterpret_cast<unsigned int*>(
                    &Ps[w][lr][mf * 16 + lg * 4 + rp * 2]) = pk.u;
            }

        // ---- rescale O ----
#pragma unroll
        for (int r = 0; r < 4; ++r) {
            float f = __shfl(fscale, lg * 4 + r);
#pragma unroll
            for (int nf = 0; nf < 4; ++nf) o_acc[nf][r] *= f;
        }

        // ---- O += P @ V ----
#pragma unroll
        for (int s = 0; s < 2; ++s) {
            half8 pa = *reinterpret_cast<const half8*>(&Ps[w][lr][s * 32 + lg * 8]);
#pragma unroll
            for (int nf = 0; nf < 4; ++nf) {
                half8 vb = *reinterpret_cast<const half8*>(&Vs[nf * 16 + lr][s * 32 + lg * 8]);
                o_acc[nf] = __builtin_amdgcn_mfma_f32_16x16x32_f16(pa, vb, o_acc[nf], 0, 0, 0);
            }
        }

        __syncthreads();
    }

    // ---- store partials (no normalization) ----
#pragma unroll
    for (int r = 0; r < 4; ++r) {
        const int qrow = q0 + w * 16 + lg * 4 + r;
#pragma unroll
        for (int nf = 0; nf < 4; ++nf)
            Op[(poff + qrow) * HDIM + nf * 16 + lr] = o_acc[nf][r];
    }
    if (lg == 0) {
        const int qrow = q0 + w * 16 + lr;
        reinterpret_cast<float2*>(ml)[poff + qrow] = make_float2(m_s, l_s);
    }
}

// ---------------------------------------------------------------------------
// Merge the KVSPLIT partials -> hd (f16, heads layout).
// Grid (SEQ/64, H, B), block 256.
// ---------------------------------------------------------------------------
__global__ __launch_bounds__(256) void attn_merge(const float* __restrict__ Op,
                                                  const float* __restrict__ ml,
                                                  _Float16* __restrict__ hd) {
    const int t  = threadIdx.x;
    const int q  = blockIdx.x * 64 + (t >> 2);
    const int d0 = (t & 3) * 16;
    const int h  = blockIdx.y;
    const int b  = blockIdx.z;

    const size_t off0 = ((size_t)b * NHEADS + h) * SEQ + q;
    const size_t off1 = ((size_t)(BATCH + b) * NHEADS + h) * SEQ + q;

    float2 ml0 = reinterpret_cast<const float2*>(ml)[off0];
    float2 ml1 = reinterpret_cast<const float2*>(ml)[off1];
    float m  = fmaxf(ml0.x, ml1.x);
    float a0 = exp2f(ml0.x - m);
    float a1 = exp2f(ml1.x - m);
    float inv = 1.0f / (ml0.y * a0 + ml1.y * a1);
    a0 *= inv; a1 *= inv;

    const float* p0 = Op + off0 * HDIM + d0;
    const float* p1 = Op + off1 * HDIM + d0;
    half8 o[2];
#pragma unroll
    for (int i = 0; i < 4; ++i) {
        float4 v0 = reinterpret_cast<const float4*>(p0)[i];
        float4 v1 = reinterpret_cast<const float4*>(p1)[i];
        o[i >> 1][(i & 1) * 4 + 0] = (_Float16)(v0.x * a0 + v1.x * a1);
        o[i >> 1][(i & 1) * 4 + 1] = (_Float16)(v0.y * a0 + v1.y * a1);
        o[i >> 1][(i & 1) * 4 + 2] = (_Float16)(v0.z * a0 + v1.z * a1);
        o[i >> 1][(i & 1) * 4 + 3] = (_Float16)(v0.w * a0 + v1.w * a1);
    }
    _Float16* dst = hd + (size_t)(b * SEQ + q) * PROJ + h * HDIM + d0;
    *reinterpret_cast<half8*>(dst)     = o[0];
    *reinterpret_cast<half8*>(dst + 8) = o[1];
}

// ---------------------------------------------------------------------------
extern "C" void kernel_launch(void* const* d_in, const int* in_sizes, int n_in,
                              void* d_out, int out_size, void* d_ws, size_t ws_size,
                              hipStream_t stream) {
    const float* x  = (const float*)d_in[0];   // (BL, EMBED)
    const float* pW = (const float*)d_in[1];   // (EMBED, PROJ)
    const float* pb = (const float*)d_in[2];   // (PROJ)
    const float* Wq = (const float*)d_in[3];   // (PROJ, PROJ)
    const float* Wk = (const float*)d_in[4];
    const float* Wv = (const float*)d_in[5];
    const float* oW = (const float*)d_in[6];   // (PROJ, EMBED)
    float* out = (float*)d_out;                // (BL, EMBED) fp32

    _Float16* ws    = (_Float16*)d_ws;
    _Float16* p_h   = ws;                                  // BL x PROJ
    _Float16* qkv   = p_h + (size_t)BL * PROJ;             // BL x 1536
    _Float16* hd    = qkv + (size_t)BL * QKVN;             // BL x PROJ
    _Float16* pWt   = hd + (size_t)BL * PROJ;              // PROJ x EMBED
    _Float16* qkvWt = pWt + (size_t)PROJ * EMBED;          // 1536 x PROJ
    _Float16* oWt   = qkvWt + (size_t)QKVN * PROJ;         // EMBED x PROJ
    _Float16* vtb   = oWt + (size_t)EMBED * PROJ;          // B*H*HDIM x SEQ
    float*    Opart = (float*)(vtb + (size_t)BATCH * NHEADS * HDIM * SEQ);  // 2*B*H*SEQ*HDIM f32
    float*    mlb   = Opart + (size_t)KVSPLIT * BATCH * NHEADS * SEQ * HDIM; // 2*B*H*SEQ float2

    dim3 blk(256);

    // ---- weight prep (attn scale * log2e folded into Wq) ----
    trconv<<<dim3(PROJ / 64, EMBED / 64), blk, 0, stream>>>(pW, pWt, EMBED, PROJ, 1.0f);
    trconv<<<dim3(PROJ / 64, PROJ / 64), blk, 0, stream>>>(Wq, qkvWt, PROJ, PROJ, 0.125f * 1.44269504f);
    trconv<<<dim3(PROJ / 64, PROJ / 64), blk, 0, stream>>>(Wk, qkvWt + (size_t)PROJ * PROJ, PROJ, PROJ, 1.0f);
    trconv<<<dim3(PROJ / 64, PROJ / 64), blk, 0, stream>>>(Wv, qkvWt + (size_t)2 * PROJ * PROJ, PROJ, PROJ, 1.0f);
    trconv<<<dim3(EMBED / 64, PROJ / 64), blk, 0, stream>>>(oW, oWt, PROJ, EMBED, 1.0f);

    // ---- p = relu(x @ pW + b), f16 out ----
    gemm_mfma<1, 1, 0><<<dim3(PROJ / 64, BL / 64), blk, 0, stream>>>(
        (const void*)x, pWt, pb, (void*)p_h, BL, PROJ, EMBED);

    // ---- fused q|k|v = p @ [Wq|Wk|Wv], f16 out ----
    gemm_mfma<0, 0, 0><<<dim3(QKVN / 64, BL / 64), blk, 0, stream>>>(
        (const void*)p_h, qkvWt, nullptr, (void*)qkv, BL, QKVN, PROJ);

    // ---- pre-transpose V per head ----
    trans_v<<<dim3(SEQ / 64, NHEADS, BATCH), blk, 0, stream>>>(qkv + 2 * PROJ, vtb);

    // ---- attention: split-KV partials + merge ----
    attn_part<<<dim3((SEQ / 64) * KVSPLIT, NHEADS, BATCH), blk, 0, stream>>>(
        qkv, qkv + PROJ, vtb, Opart, mlb);
    attn_merge<<<dim3(SEQ / 64, NHEADS, BATCH), blk, 0, stream>>>(Opart, mlb, hd);

    // ---- out = heads @ oW, fp32 out ----
    gemm_mfma<0, 0, 1><<<dim3(EMBED / 64, BL / 64), blk, 0, stream>>>(
        (const void*)hd, oWt, nullptr, (void*)out, BL, EMBED, PROJ);
}

// Round 9
// 115.355 us; speedup vs baseline: 1.0657x; 1.0657x over previous
//
#include <hip/hip_runtime.h>
#include <math.h>

#define BATCH 2
#define SEQ 2048
#define BL (BATCH * SEQ)      // 4096
#define EMBED 1024
#define PROJ 512
#define NHEADS 8
#define HDIM 64
#define QKVN (3 * PROJ)       // 1536 fused q|k|v columns
#define KVSPLIT 4
#define KVQ (SEQ / KVSPLIT)   // 512

typedef _Float16 half8 __attribute__((ext_vector_type(8)));
typedef __fp16 fp16x2 __attribute__((ext_vector_type(2)));   // cvt_pkrtz result type
typedef float floatx4 __attribute__((ext_vector_type(4)));

// ---------------------------------------------------------------------------
// Weight prep: dst[n][k] = (f16)(src[k][n] * scale)   (transpose + convert)
// ---------------------------------------------------------------------------
__global__ __launch_bounds__(256) void trconv(const float* __restrict__ src,
                                              _Float16* __restrict__ dst,
                                              int K, int N, float scale) {
    __shared__ float tile[64][65];
    const int t  = threadIdx.x;
    const int n0 = blockIdx.x * 64;
    const int k0 = blockIdx.y * 64;
    const int tx = t & 63;
    const int ty = t >> 6;   // 0..3
#pragma unroll
    for (int i = 0; i < 16; ++i) {
        int k = ty * 16 + i;
        tile[k][tx] = src[(size_t)(k0 + k) * N + n0 + tx];
    }
    __syncthreads();
#pragma unroll
    for (int i = 0; i < 16; ++i) {
        int n = ty * 16 + i;
        dst[(size_t)(n0 + n) * K + k0 + tx] = (_Float16)(tile[tx][n] * scale);
    }
}

// ---------------------------------------------------------------------------
// V pre-transpose: v (f16, rows stride QKVN, head h cols 64) -> vt[b][h][d][SEQ]
// ---------------------------------------------------------------------------
__global__ __launch_bounds__(256) void trans_v(const _Float16* __restrict__ v,
                                               _Float16* __restrict__ vt) {
    __shared__ _Float16 tile[64][72];
    const int t  = threadIdx.x;
    const int t0 = blockIdx.x * 64;
    const int h  = blockIdx.y;
    const int b  = blockIdx.z;
    {
        const int r = t >> 2, c0 = (t & 3) * 16;
        const _Float16* src = v + (size_t)(b * SEQ + t0 + r) * QKVN + h * HDIM + c0;
        *reinterpret_cast<half8*>(&tile[r][c0])     = *reinterpret_cast<const half8*>(src);
        *reinterpret_cast<half8*>(&tile[r][c0 + 8]) = *reinterpret_cast<const half8*>(src + 8);
    }
    __syncthreads();
    {
        const int c = t >> 2, k0 = (t & 3) * 16;
        half8 o1, o2;
#pragma unroll
        for (int i = 0; i < 8; ++i) { o1[i] = tile[k0 + i][c]; o2[i] = tile[k0 + 8 + i][c]; }
        _Float16* dst = vt + ((size_t)(b * NHEADS + h) * HDIM + c) * SEQ + t0 + k0;
        *reinterpret_cast<half8*>(dst)     = o1;
        *reinterpret_cast<half8*>(dst + 8) = o2;
    }
}

// ---------------------------------------------------------------------------
// f16 MFMA GEMM: C[M][N] = A[M][K] @ Bt[N][K]^T (+bias, relu), fp32 accum.
// Block tile BM x BN, BK=32, 256 threads = 4 waves (2x2, each (BM/2)x(BN/2)).
// ---------------------------------------------------------------------------
template <int BM, int BN, int A_F32, int BIASRELU, int C_F32>
__global__ __launch_bounds__(256) void gemm_mfma(const void* __restrict__ Ap,
                                                 const _Float16* __restrict__ Bt,
                                                 const float* __restrict__ bias,
                                                 void* __restrict__ Cp,
                                                 int M, int N, int K) {
    __shared__ _Float16 Ah[BM][40];
    __shared__ _Float16 Bh[BN][40];

    constexpr int MF = BM / 32;          // m-frags per wave
    constexpr int NF = BN / 32;          // n-frags per wave
    constexpr int EPA = BM / 8;          // A f16/thread (8 or 16)
    constexpr int TPA = 32 / EPA;        // threads per A row (4 or 2)
    constexpr int EPB = BN / 8;
    constexpr int TPB = 32 / EPB;

    const int t  = threadIdx.x;
    const int w  = t >> 6;
    const int l  = t & 63;
    const int lr = l & 15;
    const int lg = l >> 4;
    const int bm = blockIdx.y * BM;
    const int bn = blockIdx.x * BN;
    const int wr = w >> 1;
    const int wc = w & 1;

    const int ar = t / TPA, ac = (t % TPA) * EPA;
    const int br = t / TPB, bc = (t % TPB) * EPB;

    floatx4 acc[MF][NF];
#pragma unroll
    for (int i = 0; i < MF; ++i)
#pragma unroll
        for (int j = 0; j < NF; ++j) acc[i][j] = (floatx4){0.f, 0.f, 0.f, 0.f};

    float4 af[EPA / 4];
    half8  ah[EPA / 8];
    half8  bh[EPB / 8];

    const float* Af = (const float*)Ap;
    const _Float16* Ah16 = (const _Float16*)Ap;

    if (A_F32) {
#pragma unroll
        for (int i = 0; i < EPA / 4; ++i)
            af[i] = *reinterpret_cast<const float4*>(&Af[(size_t)(bm + ar) * K + ac + i * 4]);
    } else {
#pragma unroll
        for (int i = 0; i < EPA / 8; ++i)
            ah[i] = *reinterpret_cast<const half8*>(&Ah16[(size_t)(bm + ar) * K + ac + i * 8]);
    }
#pragma unroll
    for (int i = 0; i < EPB / 8; ++i)
        bh[i] = *reinterpret_cast<const half8*>(&Bt[(size_t)(bn + br) * K + bc + i * 8]);

    for (int kt = 0; kt < K; kt += 32) {
        if (A_F32) {
#pragma unroll
            for (int i = 0; i < EPA / 8; ++i) {
                half8 hcv;
                float4 a0 = af[2 * i], a1 = af[2 * i + 1];
                hcv[0] = (_Float16)a0.x; hcv[1] = (_Float16)a0.y;
                hcv[2] = (_Float16)a0.z; hcv[3] = (_Float16)a0.w;
                hcv[4] = (_Float16)a1.x; hcv[5] = (_Float16)a1.y;
                hcv[6] = (_Float16)a1.z; hcv[7] = (_Float16)a1.w;
                *reinterpret_cast<half8*>(&Ah[ar][ac + i * 8]) = hcv;
            }
        } else {
#pragma unroll
            for (int i = 0; i < EPA / 8; ++i)
                *reinterpret_cast<half8*>(&Ah[ar][ac + i * 8]) = ah[i];
        }
#pragma unroll
        for (int i = 0; i < EPB / 8; ++i)
            *reinterpret_cast<half8*>(&Bh[br][bc + i * 8]) = bh[i];
        __syncthreads();

        if (kt + 32 < K) {
            if (A_F32) {
#pragma unroll
                for (int i = 0; i < EPA / 4; ++i)
                    af[i] = *reinterpret_cast<const float4*>(&Af[(size_t)(bm + ar) * K + kt + 32 + ac + i * 4]);
            } else {
#pragma unroll
                for (int i = 0; i < EPA / 8; ++i)
                    ah[i] = *reinterpret_cast<const half8*>(&Ah16[(size_t)(bm + ar) * K + kt + 32 + ac + i * 8]);
            }
#pragma unroll
            for (int i = 0; i < EPB / 8; ++i)
                bh[i] = *reinterpret_cast<const half8*>(&Bt[(size_t)(bn + br) * K + kt + 32 + bc + i * 8]);
        }

        half8 afr[MF], bfr[NF];
#pragma unroll
        for (int mf = 0; mf < MF; ++mf)
            afr[mf] = *reinterpret_cast<const half8*>(&Ah[wr * (BM / 2) + mf * 16 + lr][lg * 8]);
#pragma unroll
        for (int nf = 0; nf < NF; ++nf)
            bfr[nf] = *reinterpret_cast<const half8*>(&Bh[wc * (BN / 2) + nf * 16 + lr][lg * 8]);
        __builtin_amdgcn_s_setprio(1);
#pragma unroll
        for (int mf = 0; mf < MF; ++mf)
#pragma unroll
            for (int nf = 0; nf < NF; ++nf)
                acc[mf][nf] = __builtin_amdgcn_mfma_f32_16x16x32_f16(afr[mf], bfr[nf], acc[mf][nf], 0, 0, 0);
        __builtin_amdgcn_s_setprio(0);

        __syncthreads();
    }

#pragma unroll
    for (int mf = 0; mf < MF; ++mf)
#pragma unroll
        for (int nf = 0; nf < NF; ++nf) {
            const int n = bn + wc * (BN / 2) + nf * 16 + lr;
            float bs = 0.f;
            if (BIASRELU) bs = bias[n];
#pragma unroll
            for (int r = 0; r < 4; ++r) {
                const int m = bm + wr * (BM / 2) + mf * 16 + lg * 4 + r;
                float v = acc[mf][nf][r];
                if (BIASRELU) v = fmaxf(v + bs, 0.f);
                if (C_F32)
                    ((float*)Cp)[(size_t)m * N + n] = v;
                else
                    ((_Float16*)Cp)[(size_t)m * N + n] = (_Float16)v;
            }
        }
}

// ---------------------------------------------------------------------------
// f16-MFMA flash attention, KV-split 4-way, exp2-domain, defer-rescale.
// Q,K f16 rows stride QKVN (log2e*scale folded into Wq); Vt[b][h][d][SEQ].
// Grid: ((SEQ/64)*KVSPLIT, H, B), block 256 = 4 waves x 16 q rows.
// Partials: Op[kvs][b][h][q][d] f16 (NORMALIZED by l), ml[kvs][b][h][q] float2.
// ---------------------------------------------------------------------------
__global__ __launch_bounds__(256) void attn_part(const _Float16* __restrict__ Q,
                                                 const _Float16* __restrict__ K,
                                                 const _Float16* __restrict__ Vt,
                                                 _Float16* __restrict__ Op,
                                                 float* __restrict__ ml) {
    __shared__ _Float16 Ks[64][72];
    __shared__ _Float16 Vs[64][72];
    __shared__ _Float16 Ps[4][16][72];

    const int t  = threadIdx.x;
    const int w  = t >> 6;
    const int l  = t & 63;
    const int lr = l & 15;
    const int lg = l >> 4;

    const int qt  = blockIdx.x >> 2;
    const int kvs = blockIdx.x & 3;
    const int q0  = qt * 64;
    const int h   = blockIdx.y;
    const int b   = blockIdx.z;
    const size_t base  = (size_t)b * SEQ * QKVN + (size_t)h * HDIM;
    const size_t vbase = (size_t)(b * NHEADS + h) * HDIM * SEQ;
    const size_t poff  = (((size_t)kvs * BATCH + b) * NHEADS + h) * SEQ;

    const int kt0  = kvs * KVQ;
    const int kend = kt0 + KVQ;

    // ---- Q fragments (B-operand layout), 16 q rows per wave ----
    half8 qf[2];
#pragma unroll
    for (int s = 0; s < 2; ++s) {
        const int qrow = q0 + w * 16 + lr;
        qf[s] = *reinterpret_cast<const half8*>(
            &Q[base + (size_t)qrow * QKVN + s * 32 + lg * 8]);
    }

    floatx4 o_acc[4];
#pragma unroll
    for (int j = 0; j < 4; ++j) o_acc[j] = (floatx4){0.f, 0.f, 0.f, 0.f};

    float m_s = -1e30f;
    float l_s = 0.f;

    const int rkv = t >> 2;
    const int d0  = (t & 3) * 16;

    // ---- initial prefetch ----
    half8 ka0, ka1, va0, va1;
    {
        const _Float16* kp = K + base + (size_t)(kt0 + rkv) * QKVN + d0;
        ka0 = *reinterpret_cast<const half8*>(kp);
        ka1 = *reinterpret_cast<const half8*>(kp + 8);
        const _Float16* vp = Vt + vbase + (size_t)rkv * SEQ + kt0 + d0;
        va0 = *reinterpret_cast<const half8*>(vp);
        va1 = *reinterpret_cast<const half8*>(vp + 8);
    }

    for (int kt = kt0; kt < kend; kt += 64) {
        *reinterpret_cast<half8*>(&Ks[rkv][d0])     = ka0;
        *reinterpret_cast<half8*>(&Ks[rkv][d0 + 8]) = ka1;
        *reinterpret_cast<half8*>(&Vs[rkv][d0])     = va0;
        *reinterpret_cast<half8*>(&Vs[rkv][d0 + 8]) = va1;
        __syncthreads();

        if (kt + 64 < kend) {
            const _Float16* kp = K + base + (size_t)(kt + 64 + rkv) * QKVN + d0;
            ka0 = *reinterpret_cast<const half8*>(kp);
            ka1 = *reinterpret_cast<const half8*>(kp + 8);
            const _Float16* vp = Vt + vbase + (size_t)rkv * SEQ + kt + 64 + d0;
            va0 = *reinterpret_cast<const half8*>(vp);
            va1 = *reinterpret_cast<const half8*>(vp + 8);
        }

        // ---- S^T = K @ Q^T (scores in log2 domain) ----
        floatx4 stv[4];
#pragma unroll
        for (int i = 0; i < 4; ++i) stv[i] = (floatx4){0.f, 0.f, 0.f, 0.f};
        __builtin_amdgcn_s_setprio(1);
#pragma unroll
        for (int s = 0; s < 2; ++s)
#pragma unroll
            for (int mf = 0; mf < 4; ++mf) {
                half8 kfr = *reinterpret_cast<const half8*>(&Ks[mf * 16 + lr][s * 32 + lg * 8]);
                stv[mf] = __builtin_amdgcn_mfma_f32_16x16x32_f16(kfr, qf[s], stv[mf], 0, 0, 0);
            }
        __builtin_amdgcn_s_setprio(0);

        // ---- online softmax with defer-rescale (THR = 8 in log2 units) ----
        float tm = -1e30f;
#pragma unroll
        for (int mf = 0; mf < 4; ++mf)
#pragma unroll
            for (int r = 0; r < 4; ++r) tm = fmaxf(tm, stv[mf][r]);
        tm = fmaxf(tm, __shfl_xor(tm, 16));
        tm = fmaxf(tm, __shfl_xor(tm, 32));
        if (!__all(tm <= m_s + 8.f)) {
            float mn = fmaxf(m_s, tm);
            float fs = exp2f(m_s - mn);
            m_s = mn;
            l_s *= fs;
#pragma unroll
            for (int r = 0; r < 4; ++r) {
                float f = __shfl(fs, lg * 4 + r);
#pragma unroll
                for (int nf = 0; nf < 4; ++nf) o_acc[nf][r] *= f;
            }
        }
        float sum = 0.f;
#pragma unroll
        for (int mf = 0; mf < 4; ++mf)
#pragma unroll
            for (int r = 0; r < 4; ++r) {
                float p = exp2f(stv[mf][r] - m_s);
                stv[mf][r] = p;
                sum += p;
            }
        sum += __shfl_xor(sum, 16);
        sum += __shfl_xor(sum, 32);
        l_s += sum;

        // ---- P -> wave-private LDS (PV A-layout), packed converts ----
#pragma unroll
        for (int mf = 0; mf < 4; ++mf) {
            fp16x2 pk0 = __builtin_amdgcn_cvt_pkrtz(stv[mf][0], stv[mf][1]);
            fp16x2 pk1 = __builtin_amdgcn_cvt_pkrtz(stv[mf][2], stv[mf][3]);
            *reinterpret_cast<fp16x2*>(&Ps[w][lr][mf * 16 + lg * 4])     = pk0;
            *reinterpret_cast<fp16x2*>(&Ps[w][lr][mf * 16 + lg * 4 + 2]) = pk1;
        }

        // ---- O += P @ V ----
        __builtin_amdgcn_s_setprio(1);
#pragma unroll
        for (int s = 0; s < 2; ++s) {
            half8 pa = *reinterpret_cast<const half8*>(&Ps[w][lr][s * 32 + lg * 8]);
#pragma unroll
            for (int nf = 0; nf < 4; ++nf) {
                half8 vb = *reinterpret_cast<const half8*>(&Vs[nf * 16 + lr][s * 32 + lg * 8]);
                o_acc[nf] = __builtin_amdgcn_mfma_f32_16x16x32_f16(pa, vb, o_acc[nf], 0, 0, 0);
            }
        }
        __builtin_amdgcn_s_setprio(0);

        __syncthreads();
    }

    // ---- store NORMALIZED partials (f16) + (m,l) ----
#pragma unroll
    for (int r = 0; r < 4; ++r) {
        const int qrow = q0 + w * 16 + lg * 4 + r;
        float inv = 1.0f / __shfl(l_s, lg * 4 + r);
#pragma unroll
        for (int nf = 0; nf < 4; ++nf)
            Op[(poff + qrow) * HDIM + nf * 16 + lr] = (_Float16)(o_acc[nf][r] * inv);
    }
    if (lg == 0) {
        const int qrow = q0 + w * 16 + lr;
        reinterpret_cast<float2*>(ml)[poff + qrow] = make_float2(m_s, l_s);
    }
}

// ---------------------------------------------------------------------------
// Merge the KVSPLIT normalized partials -> hd (f16, heads layout).
// Grid (SEQ/64, H, B), block 256.
// ---------------------------------------------------------------------------
__global__ __launch_bounds__(256) void attn_merge(const _Float16* __restrict__ Op,
                                                  const float* __restrict__ ml,
                                                  _Float16* __restrict__ hd) {
    const int t  = threadIdx.x;
    const int q  = blockIdx.x * 64 + (t >> 2);
    const int d0 = (t & 3) * 16;
    const int h  = blockIdx.y;
    const int b  = blockIdx.z;

    size_t offs[KVSPLIT];
    float2 mls[KVSPLIT];
#pragma unroll
    for (int s = 0; s < KVSPLIT; ++s) {
        offs[s] = (((size_t)s * BATCH + b) * NHEADS + h) * SEQ + q;
        mls[s] = reinterpret_cast<const float2*>(ml)[offs[s]];
    }
    float m = mls[0].x;
#pragma unroll
    for (int s = 1; s < KVSPLIT; ++s) m = fmaxf(m, mls[s].x);
    float wgt[KVSPLIT];
    float wsum = 0.f;
#pragma unroll
    for (int s = 0; s < KVSPLIT; ++s) {
        wgt[s] = mls[s].y * exp2f(mls[s].x - m);
        wsum += wgt[s];
    }
    float inv = 1.0f / wsum;

    float o[16] = {};
#pragma unroll
    for (int s = 0; s < KVSPLIT; ++s) {
        const _Float16* p = Op + offs[s] * HDIM + d0;
        half8 a = *reinterpret_cast<const half8*>(p);
        half8 c = *reinterpret_cast<const half8*>(p + 8);
        float wv = wgt[s] * inv;
#pragma unroll
        for (int i = 0; i < 8; ++i) {
            o[i]     += wv * (float)a[i];
            o[8 + i] += wv * (float)c[i];
        }
    }
    half8 o0, o1;
#pragma unroll
    for (int i = 0; i < 8; ++i) { o0[i] = (_Float16)o[i]; o1[i] = (_Float16)o[8 + i]; }
    _Float16* dst = hd + (size_t)(b * SEQ + q) * PROJ + h * HDIM + d0;
    *reinterpret_cast<half8*>(dst)     = o0;
    *reinterpret_cast<half8*>(dst + 8) = o1;
}

// ---------------------------------------------------------------------------
extern "C" void kernel_launch(void* const* d_in, const int* in_sizes, int n_in,
                              void* d_out, int out_size, void* d_ws, size_t ws_size,
                              hipStream_t stream) {
    const float* x  = (const float*)d_in[0];   // (BL, EMBED)
    const float* pW = (const float*)d_in[1];   // (EMBED, PROJ)
    const float* pb = (const float*)d_in[2];   // (PROJ)
    const float* Wq = (const float*)d_in[3];   // (PROJ, PROJ)
    const float* Wk = (const float*)d_in[4];
    const float* Wv = (const float*)d_in[5];
    const float* oW = (const float*)d_in[6];   // (PROJ, EMBED)
    float* out = (float*)d_out;                // (BL, EMBED) fp32

    _Float16* ws    = (_Float16*)d_ws;
    _Float16* p_h   = ws;                                  // BL x PROJ
    _Float16* qkv   = p_h + (size_t)BL * PROJ;             // BL x 1536
    _Float16* hd    = qkv + (size_t)BL * QKVN;             // BL x PROJ
    _Float16* pWt   = hd + (size_t)BL * PROJ;              // PROJ x EMBED
    _Float16* qkvWt = pWt + (size_t)PROJ * EMBED;          // 1536 x PROJ
    _Float16* oWt   = qkvWt + (size_t)QKVN * PROJ;         // EMBED x PROJ
    _Float16* vtb   = oWt + (size_t)EMBED * PROJ;          // B*H*HDIM x SEQ
    _Float16* Oph   = vtb + (size_t)BATCH * NHEADS * HDIM * SEQ;  // KVSPLIT*B*H*SEQ*HDIM f16
    float*    mlb   = (float*)(Oph + (size_t)KVSPLIT * BATCH * NHEADS * SEQ * HDIM); // float2 per row

    dim3 blk(256);

    // ---- weight prep (attn scale * log2e folded into Wq) ----
    trconv<<<dim3(PROJ / 64, EMBED / 64), blk, 0, stream>>>(pW, pWt, EMBED, PROJ, 1.0f);
    trconv<<<dim3(PROJ / 64, PROJ / 64), blk, 0, stream>>>(Wq, qkvWt, PROJ, PROJ, 0.125f * 1.44269504f);
    trconv<<<dim3(PROJ / 64, PROJ / 64), blk, 0, stream>>>(Wk, qkvWt + (size_t)PROJ * PROJ, PROJ, PROJ, 1.0f);
    trconv<<<dim3(PROJ / 64, PROJ / 64), blk, 0, stream>>>(Wv, qkvWt + (size_t)2 * PROJ * PROJ, PROJ, PROJ, 1.0f);
    trconv<<<dim3(EMBED / 64, PROJ / 64), blk, 0, stream>>>(oW, oWt, PROJ, EMBED, 1.0f);

    // ---- p = relu(x @ pW + b), f16 out : 64x64 tile (A fp32) ----
    gemm_mfma<64, 64, 1, 1, 0><<<dim3(PROJ / 64, BL / 64), blk, 0, stream>>>(
        (const void*)x, pWt, pb, (void*)p_h, BL, PROJ, EMBED);

    // ---- fused q|k|v = p @ [Wq|Wk|Wv], f16 out : 128x128 tile ----
    gemm_mfma<128, 128, 0, 0, 0><<<dim3(QKVN / 128, BL / 128), blk, 0, stream>>>(
        (const void*)p_h, qkvWt, nullptr, (void*)qkv, BL, QKVN, PROJ);

    // ---- pre-transpose V per head ----
    trans_v<<<dim3(SEQ / 64, NHEADS, BATCH), blk, 0, stream>>>(qkv + 2 * PROJ, vtb);

    // ---- attention: split-KV partials + merge ----
    attn_part<<<dim3((SEQ / 64) * KVSPLIT, NHEADS, BATCH), blk, 0, stream>>>(
        qkv, qkv + PROJ, vtb, Oph, mlb);
    attn_merge<<<dim3(SEQ / 64, NHEADS, BATCH), blk, 0, stream>>>(Oph, mlb, hd);

    // ---- out = heads @ oW, fp32 out : 128x64 tile ----
    gemm_mfma<128, 64, 0, 0, 1><<<dim3(EMBED / 64, BL / 128), blk, 0, stream>>>(
        (const void*)hd, oWt, nullptr, (void*)out, BL, EMBED, PROJ);
}